// Round 2
// baseline (3197.318 us; speedup 1.0000x reference)
//
#include <hip/hip_runtime.h>
#include <cmath>

#define NR   8192   // rows of Y
#define DB   512    // signal dim n
#define NB   2048   // dictionary atoms m
#define ITERS 20
#define NSQ   9     // trace-normalized squarings of B

typedef _Float16 hfrag_t __attribute__((ext_vector_type(8)));  // 8 fp16 = 16B
typedef __attribute__((ext_vector_type(4))) float accv_t;      // 4 fp32
typedef unsigned short us4 __attribute__((ext_vector_type(4))); // 8B
typedef float f4 __attribute__((ext_vector_type(4)));           // 16B

// scalar slots in ws
#define SL_Y2   0
#define SL_NUM  1
#define SL_DEN  2
#define SL_C    3
#define SL_ETA  4
#define SL_THR  5
#define SL_TR   6    // 6..15  traces
#define SL_RES2 16   // 16..35 per-iter ||R||^2

__device__ inline unsigned short f2h(float f) {
  _Float16 h = (_Float16)f;
  return __builtin_bit_cast(unsigned short, h);
}
__device__ inline float h2f(unsigned short u) {
  _Float16 h = __builtin_bit_cast(_Float16, u);
  return (float)h;
}
__device__ inline float softthr(float x, float t) {
  float a = fabsf(x) - t;
  return a > 0.f ? copysignf(a, x) : 0.f;
}

// ---- Fragment-native tiled layout ----
// 16x16 tile = 256 contiguous fp16, element (m,k) at m*16+k (row-major in tile).
// A-fragment for mfma_16x16x32 (operand-swapped): lane (l16,quad) needs
// A[m=l16][k=quad*8+j] j=0..7 -> tile kt*2+(quad>>1), bytes l16*32+(quad&1)*16:
// ONE 16B load per fragment; wave covers 512B contiguous. Same for B (n,k).
// C tile: lane owns (m=l16, n=quad*4+r) -> us4 at byte l16*32+quad*8.

// ---- barrier-free MFMA GEMM core: both operands tiled, no LDS ----
// (round-0 proven form; compiler schedules loads across the unroll-4 window)
template<int MI, int NI, int NKT>
__device__ inline void gemm_tt(const unsigned short* __restrict__ At, int NTka,
                               const unsigned short* __restrict__ Bt, int NTkb,
                               int mt0, int nt0, accv_t acc[MI][NI]) {
  const int lane = threadIdx.x & 63;
  const int l16 = lane & 15, quad = lane >> 4;
  const int off = l16 * 16 + (quad & 1) * 8;   // element offset within tile
  const int kh = quad >> 1;
#pragma unroll
  for (int mi = 0; mi < MI; ++mi)
#pragma unroll
    for (int ni = 0; ni < NI; ++ni) acc[mi][ni] = (accv_t){0.f, 0.f, 0.f, 0.f};

#pragma unroll 4
  for (int kt = 0; kt < NKT; ++kt) {
    const int ktile = (kt << 1) + kh;
    hfrag_t af[MI], bf[NI];
#pragma unroll
    for (int mi = 0; mi < MI; ++mi)
      af[mi] = *(const hfrag_t*)&At[(((size_t)(mt0 + mi) * NTka + ktile) << 8) + off];
#pragma unroll
    for (int ni = 0; ni < NI; ++ni)
      bf[ni] = *(const hfrag_t*)&Bt[(((size_t)(nt0 + ni) * NTkb + ktile) << 8) + off];
#pragma unroll
    for (int mi = 0; mi < MI; ++mi)
#pragma unroll
      for (int ni = 0; ni < NI; ++ni)
        acc[mi][ni] = __builtin_amdgcn_mfma_f32_16x16x32_f16(bf[ni], af[mi], acc[mi][ni], 0, 0, 0);
  }
}

// C-tile epilogue offset (element units) for tiled fp16 surfaces
__device__ inline size_t ctile_off(int mt, int nt, int NTn) {
  int lane = threadIdx.x & 63;
  return (((size_t)mt * NTn + nt) << 8) + (lane & 15) * 16 + (lane >> 4) * 4;
}

// ---------------- small kernels ----------------
__global__ void k_zero(float* slots) { if (threadIdx.x < 64) slots[threadIdx.x] = 0.f; }

__global__ void k_colnorm(const float* __restrict__ W, float* __restrict__ invn) {
  int j = blockIdx.x * 256 + threadIdx.x;     // 2048 cols
  float s = 0.f;
  for (int i = 0; i < DB; ++i) { float v = W[(size_t)i * NB + j]; s += v * v; }
  invn[j] = 1.0f / sqrtf(s);
}

// normalize cols; emit tiled Wn_t [DB/16][NB/16] (elem (i,j)->i*16+j)
// and tiled Wt_t [NB/16][DB/16] (elem (j,i)->j*16+i)
__global__ void k_wnorm(const float* __restrict__ W, const float* __restrict__ invn,
                        unsigned short* __restrict__ Wn_t, unsigned short* __restrict__ Wt_t) {
  int tx = threadIdx.x & 31, ty = threadIdx.x >> 5;
  int j = blockIdx.x * 32 + tx;               // NB index
  float inv = invn[j];
#pragma unroll
  for (int r = 0; r < 4; ++r) {
    int i = blockIdx.y * 32 + ty + r * 8;     // DB index
    unsigned short h = f2h(W[(size_t)i * NB + j] * inv);
    Wn_t[(((size_t)(i >> 4) * (NB / 16) + (j >> 4)) << 8) + (i & 15) * 16 + (j & 15)] = h;
    Wt_t[(((size_t)(j >> 4) * (DB / 16) + (i >> 4)) << 8) + (j & 15) * 16 + (i & 15)] = h;
  }
}

// Y (row-major fp32) -> Yh (tiled fp16, 32 k-tiles per row) + ||Y||^2
__global__ void k_ynorm(const float* __restrict__ Y, unsigned short* __restrict__ Yh,
                        float* __restrict__ slots) {
  float s = 0.f;
  for (size_t u = (size_t)blockIdx.x * 256 + threadIdx.x; u < (size_t)(NR * DB / 4);
       u += (size_t)gridDim.x * 256) {
    int tile = (int)(u >> 6), r = (int)(u & 63);
    int mt = tile >> 5, nt = tile & 31;
    int m = mt * 16 + (r >> 2), n = nt * 16 + (r & 3) * 4;
    f4 v = *(const f4*)&Y[(size_t)m * DB + n];
    us4 h;
#pragma unroll
    for (int q = 0; q < 4; ++q) { h[q] = f2h(v[q]); s += v[q] * v[q]; }
    *(us4*)&Yh[u << 2] = h;
  }
  for (int off = 32; off > 0; off >>= 1) s += __shfl_xor(s, off);
  if ((threadIdx.x & 63) == 0) atomicAdd(&slots[SL_Y2], s);
}

// fp32 squaring: D = (S/tr)^2, accumulate trace(D)
__global__ __launch_bounds__(256) void k_sq(const float* __restrict__ S, float* __restrict__ D,
                                            const float* __restrict__ trIn, float* __restrict__ trOut) {
  __shared__ float tA[32][33], tB[32][33];
  int tx = threadIdx.x & 31, ty = threadIdx.x >> 5;
  int r0 = blockIdx.y * 32, c0 = blockIdx.x * 32;
  float inv = 1.0f / trIn[0];
  float acc[4] = {0.f, 0.f, 0.f, 0.f};
  for (int kt = 0; kt < 16; ++kt) {
    __syncthreads();
#pragma unroll
    for (int r = 0; r < 4; ++r) {
      tA[ty + r * 8][tx] = S[(size_t)(r0 + ty + r * 8) * DB + kt * 32 + tx];
      tB[ty + r * 8][tx] = S[(size_t)(kt * 32 + ty + r * 8) * DB + c0 + tx];
    }
    __syncthreads();
#pragma unroll
    for (int kk = 0; kk < 32; ++kk) {
      float b = tB[kk][tx];
#pragma unroll
      for (int r = 0; r < 4; ++r) acc[r] += tA[ty + r * 8][kk] * b;
    }
  }
  float inv2 = inv * inv;
#pragma unroll
  for (int r = 0; r < 4; ++r) {
    int row = r0 + ty + r * 8, col = c0 + tx;
    float v = acc[r] * inv2;
    D[(size_t)row * DB + col] = v;
    if (row == col) atomicAdd(trOut, v);
  }
}

__global__ void k_rayleigh(const float* __restrict__ Bm, const float* __restrict__ S,
                           float* __restrict__ slots) {
  int tid = blockIdx.x * 256 + threadIdx.x;
  float num = 0.f, den = 0.f;
  for (int i = tid; i < DB * DB; i += 256 * 256) {
    float s = S[i];
    num += Bm[i] * s;
    if ((i >> 9) == (i & 511)) den += s;
  }
  for (int off = 32; off > 0; off >>= 1) { num += __shfl_xor(num, off); den += __shfl_xor(den, off); }
  if ((threadIdx.x & 63) == 0) { atomicAdd(&slots[SL_NUM], num); atomicAdd(&slots[SL_DEN], den); }
}

__global__ void k_derive(float* slots, const float* __restrict__ Kp) {
  if (threadIdx.x == 0) {
    float cc = slots[SL_NUM] / slots[SL_DEN];
    slots[SL_C] = cc;
    float eta = 1.0f / cc;
    slots[SL_ETA] = eta;
    slots[SL_THR] = Kp[0] * eta;
  }
}

__global__ void k_norms(const float* __restrict__ slots, float* __restrict__ out) {
  int i = threadIdx.x;
  if (i < ITERS) out[i] = sqrtf(slots[SL_RES2 + i] / slots[SL_Y2]);
}

// ---------------- GEMM kernels (all barrier-free) ----------------
// B = Wn * Wn^T [512x512] row-major out, trace -> slots[SL_TR].
// block 128m x 64n: wave w covers mt0=8*by+w*2 (MI=2), nt0=4*bx (NI=4)
__global__ __launch_bounds__(256) void k_gemm_bbuild(const unsigned short* __restrict__ Wn_t,
                                                     float* __restrict__ Bm, float* __restrict__ slots) {
  accv_t acc[2][4];
  int w = threadIdx.x >> 6, lane = threadIdx.x & 63;
  int mt0 = blockIdx.y * 8 + w * 2, nt0 = blockIdx.x * 4;
  gemm_tt<2, 4, NB / 32>(Wn_t, NB / 16, Wn_t, NB / 16, mt0, nt0, acc);
  int l16 = lane & 15, quad = lane >> 4;
  float tr = 0.f;
#pragma unroll
  for (int mi = 0; mi < 2; ++mi)
#pragma unroll
    for (int ni = 0; ni < 4; ++ni) {
      int m = (mt0 + mi) * 16 + l16, nb = (nt0 + ni) * 16 + quad * 4;
      *(f4*)&Bm[(size_t)m * DB + nb] = acc[mi][ni];
#pragma unroll
      for (int r = 0; r < 4; ++r)
        if (m == nb + r) tr += acc[mi][ni][r];
    }
  if (tr != 0.f) atomicAdd(&slots[SL_TR], tr);
}

// Gamma0 = soft(eta*(Y@Wn), lam); Gh = Zh = Gamma0 (tiled).
// 1-D grid 2048, XCD-clustered: block = 128m x 64n, wave 32m x 64n (MI=2,NI=4).
__global__ __launch_bounds__(256) void k_gemm_init(const unsigned short* __restrict__ Yh,
                                                   const unsigned short* __restrict__ Wt_t,
                                                   const float* __restrict__ slots,
                                                   const float* __restrict__ Kp,
                                                   unsigned short* __restrict__ Gh,
                                                   unsigned short* __restrict__ Zh) {
  accv_t acc[2][4];
  int w = threadIdx.x >> 6;
  int h = blockIdx.x;
  int xcd = h & 7, slot = h >> 3;           // 256 slots per XCD
  int band = xcd * 8 + (slot >> 5);         // 64 bands of 128 rows
  int nt = slot & 31;                       // 32 n-groups of 64 cols
  int mt0 = band * 8 + w * 2, nt0 = nt * 4;
  gemm_tt<2, 4, DB / 32>(Yh, DB / 16, Wt_t, DB / 16, mt0, nt0, acc);
  float eta = slots[SL_ETA], lam = Kp[0];
#pragma unroll
  for (int mi = 0; mi < 2; ++mi)
#pragma unroll
    for (int ni = 0; ni < 4; ++ni) {
      size_t tb = ctile_off(mt0 + mi, nt0 + ni, NB / 16);
      us4 gq;
#pragma unroll
      for (int r = 0; r < 4; ++r) gq[r] = f2h(softthr(acc[mi][ni][r] * eta, lam));
      *(us4*)&Gh[tb] = gq;
      *(us4*)&Zh[tb] = gq;
    }
}

// R = Z @ Wn^T - Y (tiled); ||R||^2.
// 1-D grid 1024, XCD-clustered: block = 64m x 64n, wave 16m x 64n (MI=1,NI=4).
// The 8 n-blocks sharing a 64-row Zh band land on the SAME XCD -> L2 reuse.
__global__ __launch_bounds__(256) void k_gemm_res(const unsigned short* __restrict__ Zh,
                                                  const unsigned short* __restrict__ Wn_t,
                                                  const unsigned short* __restrict__ Yh,
                                                  unsigned short* __restrict__ Rh,
                                                  float* __restrict__ res2slot) {
  accv_t acc[1][4];
  int w = threadIdx.x >> 6;
  int h = blockIdx.x;
  int xcd = h & 7, slot = h >> 3;           // 128 slots per XCD
  int band = xcd * 16 + (slot >> 3);        // 128 bands of 64 rows
  int nt = slot & 7;                        // 8 n-groups of 64 cols
  int mt0 = band * 4 + w, nt0 = nt * 4;
  gemm_tt<1, 4, NB / 32>(Zh, NB / 16, Wn_t, NB / 16, mt0, nt0, acc);
  float s2 = 0.f;
#pragma unroll
  for (int ni = 0; ni < 4; ++ni) {
    size_t tb = ctile_off(mt0, nt0 + ni, DB / 16);
    us4 yq = *(const us4*)&Yh[tb];
    us4 rq;
#pragma unroll
    for (int r = 0; r < 4; ++r) {
      float rv = acc[0][ni][r] - h2f(yq[r]);
      rq[r] = f2h(rv);
      s2 += rv * rv;
    }
    *(us4*)&Rh[tb] = rq;
  }
  for (int off = 32; off > 0; off >>= 1) s2 += __shfl_xor(s2, off);
  if ((threadIdx.x & 63) == 0) atomicAdd(res2slot, s2);
}

// G = R @ Wn ; gn = soft(Z - eta*G, lam/c); Z = gn + mom*(gn-Gamma_old); Gh = gn.
// 1-D grid 2048, XCD-clustered: block = 128m x 64n, wave 32m x 64n (MI=2,NI=4).
// last iter: exact fp32 gn -> GammaOut (row-major).
__global__ __launch_bounds__(256) void k_gemm_upd(const unsigned short* __restrict__ Rh,
                                                  const unsigned short* __restrict__ Wt_t,
                                                  const float* __restrict__ slots,
                                                  unsigned short* __restrict__ Gh,
                                                  unsigned short* __restrict__ Zh,
                                                  float* __restrict__ GammaOut,
                                                  float mom, int writeFinal) {
  accv_t acc[2][4];
  int w = threadIdx.x >> 6, lane = threadIdx.x & 63;
  int h = blockIdx.x;
  int xcd = h & 7, slot = h >> 3;           // 256 slots per XCD
  int band = xcd * 8 + (slot >> 5);         // 64 bands of 128 rows
  int nt = slot & 31;                       // 32 n-groups of 64 cols
  int mt0 = band * 8 + w * 2, nt0 = nt * 4;
  gemm_tt<2, 4, DB / 32>(Rh, DB / 16, Wt_t, DB / 16, mt0, nt0, acc);
  int l16 = lane & 15, quad = lane >> 4;
  float eta = slots[SL_ETA], thr = slots[SL_THR];
#pragma unroll
  for (int mi = 0; mi < 2; ++mi)
#pragma unroll
    for (int ni = 0; ni < 4; ++ni) {
      size_t tb = ctile_off(mt0 + mi, nt0 + ni, NB / 16);
      us4 zq = *(const us4*)&Zh[tb];
      us4 gq = *(const us4*)&Gh[tb];
      us4 gho, zho;
      f4 gf;
#pragma unroll
      for (int r = 0; r < 4; ++r) {
        float z = h2f(zq[r]);
        float gold = h2f(gq[r]);
        float gn = softthr(z - eta * acc[mi][ni][r], thr);
        float zn = gn + mom * (gn - gold);
        gho[r] = f2h(gn);
        zho[r] = f2h(zn);
        gf[r] = gn;
      }
      *(us4*)&Gh[tb] = gho;
      *(us4*)&Zh[tb] = zho;
      if (writeFinal) {
        int m = (mt0 + mi) * 16 + l16, nb = (nt0 + ni) * 16 + quad * 4;
        *(f4*)&GammaOut[(size_t)m * NB + nb] = gf;
      }
    }
}

// X = Gamma @ Wn^T (row-major fp32 out).
// 1-D grid 1024, XCD-clustered: block = 64m x 64n, wave 16m x 64n (MI=1,NI=4).
__global__ __launch_bounds__(256) void k_gemm_x(const unsigned short* __restrict__ Gh,
                                                const unsigned short* __restrict__ Wn_t,
                                                float* __restrict__ X) {
  accv_t acc[1][4];
  int w = threadIdx.x >> 6, lane = threadIdx.x & 63;
  int h = blockIdx.x;
  int xcd = h & 7, slot = h >> 3;
  int band = xcd * 16 + (slot >> 3);
  int nt = slot & 7;
  int mt0 = band * 4 + w, nt0 = nt * 4;
  gemm_tt<1, 4, NB / 32>(Gh, NB / 16, Wn_t, NB / 16, mt0, nt0, acc);
  int l16 = lane & 15, quad = lane >> 4;
#pragma unroll
  for (int ni = 0; ni < 4; ++ni) {
    int m = mt0 * 16 + l16, nb = (nt0 + ni) * 16 + quad * 4;
    *(f4*)&X[(size_t)m * DB + nb] = acc[0][ni];
  }
}

extern "C" void kernel_launch(void* const* d_in, const int* in_sizes, int n_in,
                              void* d_out, int out_size, void* d_ws, size_t ws_size,
                              hipStream_t stream) {
  const float* Y  = (const float*)d_in[0];
  const float* W  = (const float*)d_in[1];
  const float* Kp = (const float*)d_in[2];

  float* Xout     = (float*)d_out;
  float* GammaOut = Xout + (size_t)NR * DB;
  float* NormsOut = GammaOut + (size_t)NR * NB;

  char* p = (char*)d_ws;
  auto carve = [&](size_t bytes) -> void* {
    void* r = (void*)p; p += (bytes + 255) & ~(size_t)255; return r;
  };
  float* slots = (float*)carve(64 * 4);
  float* invn  = (float*)carve(NB * 4);
  float* Bmat  = (float*)carve((size_t)DB * DB * 4);
  float* S0    = (float*)carve((size_t)DB * DB * 4);
  float* S1    = (float*)carve((size_t)DB * DB * 4);
  unsigned short* Wn_t = (unsigned short*)carve((size_t)DB * NB * 2);
  unsigned short* Wt_t = (unsigned short*)carve((size_t)NB * DB * 2);
  unsigned short* Yh   = (unsigned short*)carve((size_t)NR * DB * 2);
  unsigned short* Rh   = (unsigned short*)carve((size_t)NR * DB * 2);
  unsigned short* Zh   = (unsigned short*)carve((size_t)NR * NB * 2);
  unsigned short* Gh   = (unsigned short*)carve((size_t)NR * NB * 2);

  k_zero<<<1, 64, 0, stream>>>(slots);
  k_colnorm<<<NB / 256, 256, 0, stream>>>(W, invn);
  k_wnorm<<<dim3(NB / 32, DB / 32), 256, 0, stream>>>(W, invn, Wn_t, Wt_t);
  k_ynorm<<<1024, 256, 0, stream>>>(Y, Yh, slots);

  // power method replacement: B = Wn Wn^T, then 9 trace-normalized squarings + Rayleigh
  k_gemm_bbuild<<<dim3(DB / 64, DB / 128), 256, 0, stream>>>(Wn_t, Bmat, slots);
  float* ss[2] = {S0, S1};
  for (int k = 0; k < NSQ; ++k) {
    const float* in = (k == 0) ? Bmat : ss[(k + 1) & 1];
    k_sq<<<dim3(16, 16), 256, 0, stream>>>(in, ss[k & 1], slots + SL_TR + k, slots + SL_TR + k + 1);
  }
  k_rayleigh<<<256, 256, 0, stream>>>(Bmat, ss[(NSQ + 1) & 1], slots);
  k_derive<<<1, 64, 0, stream>>>(slots, Kp);

  // FISTA
  k_gemm_init<<<2048, 256, 0, stream>>>(Yh, Wt_t, slots, Kp, Gh, Zh);
  double t = 1.0;
  for (int i = 0; i < ITERS; ++i) {
    k_gemm_res<<<1024, 256, 0, stream>>>(Zh, Wn_t, Yh, Rh, slots + SL_RES2 + i);
    double tn = (1.0 + sqrt(1.0 + 4.0 * t * t)) / 2.0;
    float mom = (float)((t - 1.0) / tn);
    t = tn;
    k_gemm_upd<<<2048, 256, 0, stream>>>(Rh, Wt_t, slots, Gh, Zh, GammaOut,
                                         mom, (i == ITERS - 1) ? 1 : 0);
  }
  k_gemm_x<<<1024, 256, 0, stream>>>(Gh, Wn_t, Xout);
  k_norms<<<1, 64, 0, stream>>>(slots, NormsOut);
}

// Round 3
// 2837.468 us; speedup vs baseline: 1.1268x; 1.1268x over previous
//
#include <hip/hip_runtime.h>
#include <cmath>

#define NR   8192   // rows of Y
#define DB   512    // signal dim n
#define NB   2048   // dictionary atoms m
#define ITERS 20
#define NSQ   9     // trace-normalized squarings of B

typedef _Float16 hfrag_t __attribute__((ext_vector_type(8)));  // 8 fp16 = 16B
typedef __attribute__((ext_vector_type(4))) float accv_t;      // 4 fp32
typedef unsigned short us4 __attribute__((ext_vector_type(4))); // 8B
typedef float f4 __attribute__((ext_vector_type(4)));           // 16B

// scalar slots in ws
#define SL_Y2   0
#define SL_NUM  1
#define SL_DEN  2
#define SL_C    3
#define SL_ETA  4
#define SL_THR  5
#define SL_TR   6    // 6..15  traces
#define SL_RES2 16   // 16..35 per-iter ||R||^2

__device__ inline unsigned short f2h(float f) {
  _Float16 h = (_Float16)f;
  return __builtin_bit_cast(unsigned short, h);
}
__device__ inline float h2f(unsigned short u) {
  _Float16 h = __builtin_bit_cast(_Float16, u);
  return (float)h;
}
__device__ inline float softthr(float x, float t) {
  float a = fabsf(x) - t;
  return a > 0.f ? copysignf(a, x) : 0.f;
}

// async 16B/lane global->LDS copy; l is the WAVE-UNIFORM chunk base
// (HW writes lane i at l + i*16); g is per-lane.
__device__ inline void ld_lds16(const unsigned short* g, unsigned short* l) {
  __builtin_amdgcn_global_load_lds(
      (const __attribute__((address_space(1))) unsigned int*)g,
      (__attribute__((address_space(3))) unsigned int*)l, 16, 0, 0);
}

// ---- Fragment-native tiled layout ----
// 16x16 tile = 256 contiguous fp16, element (m,k) at m*16+k (row-major in tile).
// A-fragment for mfma_16x16x32 (operand-swapped): lane (l16,quad) needs
// A[m=l16][k=quad*8+j] j=0..7 -> tile kt*2+(quad>>1), elem off l16*16+(quad&1)*8.
// C tile: lane owns (m=l16, n=quad*4+r) -> us4 at elem l16*16+quad*4.

// ---- direct barrier-free core (kept for the small bbuild GEMM) ----
template<int MI, int NI, int NKT>
__device__ inline void gemm_tt(const unsigned short* __restrict__ At, int NTka,
                               const unsigned short* __restrict__ Bt, int NTkb,
                               int mt0, int nt0, accv_t acc[MI][NI]) {
  const int lane = threadIdx.x & 63;
  const int l16 = lane & 15, quad = lane >> 4;
  const int off = l16 * 16 + (quad & 1) * 8;
  const int kh = quad >> 1;
#pragma unroll
  for (int mi = 0; mi < MI; ++mi)
#pragma unroll
    for (int ni = 0; ni < NI; ++ni) acc[mi][ni] = (accv_t){0.f, 0.f, 0.f, 0.f};
#pragma unroll 4
  for (int kt = 0; kt < NKT; ++kt) {
    const int ktile = (kt << 1) + kh;
    hfrag_t af[MI], bf[NI];
#pragma unroll
    for (int mi = 0; mi < MI; ++mi)
      af[mi] = *(const hfrag_t*)&At[(((size_t)(mt0 + mi) * NTka + ktile) << 8) + off];
#pragma unroll
    for (int ni = 0; ni < NI; ++ni)
      bf[ni] = *(const hfrag_t*)&Bt[(((size_t)(nt0 + ni) * NTkb + ktile) << 8) + off];
#pragma unroll
    for (int mi = 0; mi < MI; ++mi)
#pragma unroll
      for (int ni = 0; ni < NI; ++ni)
        acc[mi][ni] = __builtin_amdgcn_mfma_f32_16x16x32_f16(bf[ni], af[mi], acc[mi][ni], 0, 0, 0);
  }
}

// ---- LDS-staged double-buffered core (m97 structure) ----
// Block tile (WM*MI*16) x (WN*NI*16), 4 waves arranged WM x WN, K-stage = 64 elems
// (BKT=4 sixteen-tiles). Staging is a LINEAR copy of 1KB chunks (tile layout
// preserved in LDS), so fragment reads use identical offsets as gemm_tt.
template<int MI, int NI, int WM, int WN, int NKT>
__device__ inline void gemm_lds(const unsigned short* __restrict__ At, int NTka,
                                const unsigned short* __restrict__ Bt, int NTkb,
                                int mtB, int ntB, accv_t acc[MI][NI],
                                unsigned short* sA, unsigned short* sB) {
  constexpr int BMT = WM * MI, BNT = WN * NI, BKT = 4;
  constexpr int NST = NKT / BKT;               // stages
  constexpr int ASZ = BMT * BKT * 256;         // elems per A buffer
  constexpr int BSZ = BNT * BKT * 256;         // elems per B buffer
  const int w = threadIdx.x >> 6, lane = threadIdx.x & 63;
  const int wy = w / WN, wx = w % WN;
  const int l16 = lane & 15, quad = lane >> 4;
  const int foff = l16 * 16 + (quad & 1) * 8;  // elem offset within tile
  const int kh = quad >> 1;

#pragma unroll
  for (int mi = 0; mi < MI; ++mi)
#pragma unroll
    for (int ni = 0; ni < NI; ++ni) acc[mi][ni] = (accv_t){0.f, 0.f, 0.f, 0.f};

  auto stage = [&](int s, int b) {
    const int kb = s * BKT;
    // A: BMT*2 chunks of 1KB (512 elems); wave w takes every 4th
#pragma unroll
    for (int i = 0; i < BMT / 2; ++i) {
      int c = i * 4 + w;
      int mt = c >> 1, half = c & 1;
      const unsigned short* g =
          At + (((size_t)(mtB + mt) * NTka + kb) << 8) + (half << 9) + lane * 8;
      ld_lds16(g, sA + b * ASZ + ((mt * BKT) << 8) + (half << 9));
    }
#pragma unroll
    for (int i = 0; i < BNT / 2; ++i) {
      int c = i * 4 + w;
      int nt = c >> 1, half = c & 1;
      const unsigned short* g =
          Bt + (((size_t)(ntB + nt) * NTkb + kb) << 8) + (half << 9) + lane * 8;
      ld_lds16(g, sB + b * BSZ + ((nt * BKT) << 8) + (half << 9));
    }
  };

  auto compute = [&](int b) {
#pragma unroll
    for (int kk = 0; kk < 2; ++kk) {
      const int kt = kk * 2 + kh;
      hfrag_t af[MI], bf[NI];
#pragma unroll
      for (int mi = 0; mi < MI; ++mi) {
        int mt = wy * MI + mi;
        af[mi] = *(const hfrag_t*)&sA[b * ASZ + ((mt * BKT + kt) << 8) + foff];
      }
#pragma unroll
      for (int ni = 0; ni < NI; ++ni) {
        int nt = wx * NI + ni;
        bf[ni] = *(const hfrag_t*)&sB[b * BSZ + ((nt * BKT + kt) << 8) + foff];
      }
#pragma unroll
      for (int mi = 0; mi < MI; ++mi)
#pragma unroll
        for (int ni = 0; ni < NI; ++ni)
          acc[mi][ni] = __builtin_amdgcn_mfma_f32_16x16x32_f16(bf[ni], af[mi], acc[mi][ni], 0, 0, 0);
    }
  };

  stage(0, 0);
  __syncthreads();                 // drains vmcnt(0): buf0 ready
  for (int s = 0; s < NST; ++s) {
    if (s + 1 < NST) stage(s + 1, (s + 1) & 1);
    compute(s & 1);
    __syncthreads();               // readers done + next-stage DMA drained
  }
}

// C-tile epilogue offset (element units) for tiled fp16 surfaces
__device__ inline size_t ctile_off(int mt, int nt, int NTn) {
  int lane = threadIdx.x & 63;
  return (((size_t)mt * NTn + nt) << 8) + (lane & 15) * 16 + (lane >> 4) * 4;
}

// ---------------- small kernels ----------------
__global__ void k_zero(float* slots) { if (threadIdx.x < 64) slots[threadIdx.x] = 0.f; }

__global__ void k_colnorm(const float* __restrict__ W, float* __restrict__ invn) {
  int j = blockIdx.x * 256 + threadIdx.x;     // 2048 cols
  float s = 0.f;
  for (int i = 0; i < DB; ++i) { float v = W[(size_t)i * NB + j]; s += v * v; }
  invn[j] = 1.0f / sqrtf(s);
}

// normalize cols; emit tiled Wn_t [DB/16][NB/16] and tiled Wt_t [NB/16][DB/16]
__global__ void k_wnorm(const float* __restrict__ W, const float* __restrict__ invn,
                        unsigned short* __restrict__ Wn_t, unsigned short* __restrict__ Wt_t) {
  int tx = threadIdx.x & 31, ty = threadIdx.x >> 5;
  int j = blockIdx.x * 32 + tx;               // NB index
  float inv = invn[j];
#pragma unroll
  for (int r = 0; r < 4; ++r) {
    int i = blockIdx.y * 32 + ty + r * 8;     // DB index
    unsigned short h = f2h(W[(size_t)i * NB + j] * inv);
    Wn_t[(((size_t)(i >> 4) * (NB / 16) + (j >> 4)) << 8) + (i & 15) * 16 + (j & 15)] = h;
    Wt_t[(((size_t)(j >> 4) * (DB / 16) + (i >> 4)) << 8) + (j & 15) * 16 + (i & 15)] = h;
  }
}

// Y (row-major fp32) -> Yh (tiled fp16) + ||Y||^2
__global__ void k_ynorm(const float* __restrict__ Y, unsigned short* __restrict__ Yh,
                        float* __restrict__ slots) {
  float s = 0.f;
  for (size_t u = (size_t)blockIdx.x * 256 + threadIdx.x; u < (size_t)(NR * DB / 4);
       u += (size_t)gridDim.x * 256) {
    int tile = (int)(u >> 6), r = (int)(u & 63);
    int mt = tile >> 5, nt = tile & 31;
    int m = mt * 16 + (r >> 2), n = nt * 16 + (r & 3) * 4;
    f4 v = *(const f4*)&Y[(size_t)m * DB + n];
    us4 h;
#pragma unroll
    for (int q = 0; q < 4; ++q) { h[q] = f2h(v[q]); s += v[q] * v[q]; }
    *(us4*)&Yh[u << 2] = h;
  }
  for (int off = 32; off > 0; off >>= 1) s += __shfl_xor(s, off);
  if ((threadIdx.x & 63) == 0) atomicAdd(&slots[SL_Y2], s);
}

// fp32 squaring: D = (S/tr)^2, accumulate trace(D)
__global__ __launch_bounds__(256) void k_sq(const float* __restrict__ S, float* __restrict__ D,
                                            const float* __restrict__ trIn, float* __restrict__ trOut) {
  __shared__ float tA[32][33], tB[32][33];
  int tx = threadIdx.x & 31, ty = threadIdx.x >> 5;
  int r0 = blockIdx.y * 32, c0 = blockIdx.x * 32;
  float inv = 1.0f / trIn[0];
  float acc[4] = {0.f, 0.f, 0.f, 0.f};
  for (int kt = 0; kt < 16; ++kt) {
    __syncthreads();
#pragma unroll
    for (int r = 0; r < 4; ++r) {
      tA[ty + r * 8][tx] = S[(size_t)(r0 + ty + r * 8) * DB + kt * 32 + tx];
      tB[ty + r * 8][tx] = S[(size_t)(kt * 32 + ty + r * 8) * DB + c0 + tx];
    }
    __syncthreads();
#pragma unroll
    for (int kk = 0; kk < 32; ++kk) {
      float b = tB[kk][tx];
#pragma unroll
      for (int r = 0; r < 4; ++r) acc[r] += tA[ty + r * 8][kk] * b;
    }
  }
  float inv2 = inv * inv;
#pragma unroll
  for (int r = 0; r < 4; ++r) {
    int row = r0 + ty + r * 8, col = c0 + tx;
    float v = acc[r] * inv2;
    D[(size_t)row * DB + col] = v;
    if (row == col) atomicAdd(trOut, v);
  }
}

__global__ void k_rayleigh(const float* __restrict__ Bm, const float* __restrict__ S,
                           float* __restrict__ slots) {
  int tid = blockIdx.x * 256 + threadIdx.x;
  float num = 0.f, den = 0.f;
  for (int i = tid; i < DB * DB; i += 256 * 256) {
    float s = S[i];
    num += Bm[i] * s;
    if ((i >> 9) == (i & 511)) den += s;
  }
  for (int off = 32; off > 0; off >>= 1) { num += __shfl_xor(num, off); den += __shfl_xor(den, off); }
  if ((threadIdx.x & 63) == 0) { atomicAdd(&slots[SL_NUM], num); atomicAdd(&slots[SL_DEN], den); }
}

__global__ void k_derive(float* slots, const float* __restrict__ Kp) {
  if (threadIdx.x == 0) {
    float cc = slots[SL_NUM] / slots[SL_DEN];
    slots[SL_C] = cc;
    float eta = 1.0f / cc;
    slots[SL_ETA] = eta;
    slots[SL_THR] = Kp[0] * eta;
  }
}

__global__ void k_norms(const float* __restrict__ slots, float* __restrict__ out) {
  int i = threadIdx.x;
  if (i < ITERS) out[i] = sqrtf(slots[SL_RES2 + i] / slots[SL_Y2]);
}

// ---------------- GEMM kernels ----------------
// B = Wn * Wn^T [512x512] row-major out, trace -> slots[SL_TR]. (direct core)
__global__ __launch_bounds__(256) void k_gemm_bbuild(const unsigned short* __restrict__ Wn_t,
                                                     float* __restrict__ Bm, float* __restrict__ slots) {
  accv_t acc[2][4];
  int w = threadIdx.x >> 6, lane = threadIdx.x & 63;
  int mt0 = blockIdx.y * 8 + w * 2, nt0 = blockIdx.x * 4;
  gemm_tt<2, 4, NB / 32>(Wn_t, NB / 16, Wn_t, NB / 16, mt0, nt0, acc);
  int l16 = lane & 15, quad = lane >> 4;
  float tr = 0.f;
#pragma unroll
  for (int mi = 0; mi < 2; ++mi)
#pragma unroll
    for (int ni = 0; ni < 4; ++ni) {
      int m = (mt0 + mi) * 16 + l16, nb = (nt0 + ni) * 16 + quad * 4;
      *(f4*)&Bm[(size_t)m * DB + nb] = acc[mi][ni];
#pragma unroll
      for (int r = 0; r < 4; ++r)
        if (m == nb + r) tr += acc[mi][ni][r];
    }
  if (tr != 0.f) atomicAdd(&slots[SL_TR], tr);
}

// Gamma0 = soft(eta*(Y@Wn), lam); Gh = Zh = Gamma0. block 128x128, wave 64x64.
__global__ __launch_bounds__(256) void k_gemm_init(const unsigned short* __restrict__ Yh,
                                                   const unsigned short* __restrict__ Wt_t,
                                                   const float* __restrict__ slots,
                                                   const float* __restrict__ Kp,
                                                   unsigned short* __restrict__ Gh,
                                                   unsigned short* __restrict__ Zh) {
  __shared__ unsigned short sA[2 * 8 * 4 * 256];
  __shared__ unsigned short sB[2 * 8 * 4 * 256];
  accv_t acc[4][4];
  int w = threadIdx.x >> 6;
  int mtB = blockIdx.y * 8, ntB = blockIdx.x * 8;
  gemm_lds<4, 4, 2, 2, DB / 16>(Yh, DB / 16, Wt_t, DB / 16, mtB, ntB, acc, sA, sB);
  int mt0 = mtB + (w >> 1) * 4, nt0 = ntB + (w & 1) * 4;
  float eta = slots[SL_ETA], lam = Kp[0];
#pragma unroll
  for (int mi = 0; mi < 4; ++mi)
#pragma unroll
    for (int ni = 0; ni < 4; ++ni) {
      size_t tb = ctile_off(mt0 + mi, nt0 + ni, NB / 16);
      us4 gq;
#pragma unroll
      for (int r = 0; r < 4; ++r) gq[r] = f2h(softthr(acc[mi][ni][r] * eta, lam));
      *(us4*)&Gh[tb] = gq;
      *(us4*)&Zh[tb] = gq;
    }
}

// R = Z @ Wn^T - Y; ||R||^2. block 128m x 64n, wave 32x64 (MI=2,NI=4).
__global__ __launch_bounds__(256) void k_gemm_res(const unsigned short* __restrict__ Zh,
                                                  const unsigned short* __restrict__ Wn_t,
                                                  const unsigned short* __restrict__ Yh,
                                                  unsigned short* __restrict__ Rh,
                                                  float* __restrict__ res2slot) {
  __shared__ unsigned short sA[2 * 8 * 4 * 256];
  __shared__ unsigned short sB[2 * 4 * 4 * 256];
  accv_t acc[2][4];
  int w = threadIdx.x >> 6;
  int mtB = blockIdx.y * 8, ntB = blockIdx.x * 4;
  gemm_lds<2, 4, 4, 1, NB / 16>(Zh, NB / 16, Wn_t, NB / 16, mtB, ntB, acc, sA, sB);
  int mt0 = mtB + w * 2, nt0 = ntB;
  float s2 = 0.f;
#pragma unroll
  for (int mi = 0; mi < 2; ++mi)
#pragma unroll
    for (int ni = 0; ni < 4; ++ni) {
      size_t tb = ctile_off(mt0 + mi, nt0 + ni, DB / 16);
      us4 yq = *(const us4*)&Yh[tb];
      us4 rq;
#pragma unroll
      for (int r = 0; r < 4; ++r) {
        float rv = acc[mi][ni][r] - h2f(yq[r]);
        rq[r] = f2h(rv);
        s2 += rv * rv;
      }
      *(us4*)&Rh[tb] = rq;
    }
  for (int off = 32; off > 0; off >>= 1) s2 += __shfl_xor(s2, off);
  if ((threadIdx.x & 63) == 0) atomicAdd(res2slot, s2);
}

// G = R @ Wn ; gn = soft(Z - eta*G, lam/c); Z = gn + mom*(gn-Gamma_old); Gh = gn.
// block 128x128, wave 64x64. last iter: exact fp32 gn -> GammaOut (row-major).
__global__ __launch_bounds__(256) void k_gemm_upd(const unsigned short* __restrict__ Rh,
                                                  const unsigned short* __restrict__ Wt_t,
                                                  const float* __restrict__ slots,
                                                  unsigned short* __restrict__ Gh,
                                                  unsigned short* __restrict__ Zh,
                                                  float* __restrict__ GammaOut,
                                                  float mom, int writeFinal) {
  __shared__ unsigned short sA[2 * 8 * 4 * 256];
  __shared__ unsigned short sB[2 * 8 * 4 * 256];
  accv_t acc[4][4];
  int w = threadIdx.x >> 6, lane = threadIdx.x & 63;
  int mtB = blockIdx.y * 8, ntB = blockIdx.x * 8;
  gemm_lds<4, 4, 2, 2, DB / 16>(Rh, DB / 16, Wt_t, DB / 16, mtB, ntB, acc, sA, sB);
  int mt0 = mtB + (w >> 1) * 4, nt0 = ntB + (w & 1) * 4;
  int l16 = lane & 15, quad = lane >> 4;
  float eta = slots[SL_ETA], thr = slots[SL_THR];
#pragma unroll
  for (int mi = 0; mi < 4; ++mi)
#pragma unroll
    for (int ni = 0; ni < 4; ++ni) {
      size_t tb = ctile_off(mt0 + mi, nt0 + ni, NB / 16);
      us4 zq = *(const us4*)&Zh[tb];
      us4 gq = *(const us4*)&Gh[tb];
      us4 gho, zho;
      f4 gf;
#pragma unroll
      for (int r = 0; r < 4; ++r) {
        float z = h2f(zq[r]);
        float gold = h2f(gq[r]);
        float gn = softthr(z - eta * acc[mi][ni][r], thr);
        float zn = gn + mom * (gn - gold);
        gho[r] = f2h(gn);
        zho[r] = f2h(zn);
        gf[r] = gn;
      }
      *(us4*)&Gh[tb] = gho;
      *(us4*)&Zh[tb] = zho;
      if (writeFinal) {
        int m = (mt0 + mi) * 16 + l16, nb = (nt0 + ni) * 16 + quad * 4;
        *(f4*)&GammaOut[(size_t)m * NB + nb] = gf;
      }
    }
}

// X = Gamma @ Wn^T (row-major fp32 out). block 128m x 64n, wave 32x64.
__global__ __launch_bounds__(256) void k_gemm_x(const unsigned short* __restrict__ Gh,
                                                const unsigned short* __restrict__ Wn_t,
                                                float* __restrict__ X) {
  __shared__ unsigned short sA[2 * 8 * 4 * 256];
  __shared__ unsigned short sB[2 * 4 * 4 * 256];
  accv_t acc[2][4];
  int w = threadIdx.x >> 6, lane = threadIdx.x & 63;
  int mtB = blockIdx.y * 8, ntB = blockIdx.x * 4;
  gemm_lds<2, 4, 4, 1, NB / 16>(Gh, NB / 16, Wn_t, NB / 16, mtB, ntB, acc, sA, sB);
  int mt0 = mtB + w * 2, nt0 = ntB;
  int l16 = lane & 15, quad = lane >> 4;
#pragma unroll
  for (int mi = 0; mi < 2; ++mi)
#pragma unroll
    for (int ni = 0; ni < 4; ++ni) {
      int m = (mt0 + mi) * 16 + l16, nb = (nt0 + ni) * 16 + quad * 4;
      *(f4*)&X[(size_t)m * DB + nb] = acc[mi][ni];
    }
}

extern "C" void kernel_launch(void* const* d_in, const int* in_sizes, int n_in,
                              void* d_out, int out_size, void* d_ws, size_t ws_size,
                              hipStream_t stream) {
  const float* Y  = (const float*)d_in[0];
  const float* W  = (const float*)d_in[1];
  const float* Kp = (const float*)d_in[2];

  float* Xout     = (float*)d_out;
  float* GammaOut = Xout + (size_t)NR * DB;
  float* NormsOut = GammaOut + (size_t)NR * NB;

  char* p = (char*)d_ws;
  auto carve = [&](size_t bytes) -> void* {
    void* r = (void*)p; p += (bytes + 255) & ~(size_t)255; return r;
  };
  float* slots = (float*)carve(64 * 4);
  float* invn  = (float*)carve(NB * 4);
  float* Bmat  = (float*)carve((size_t)DB * DB * 4);
  float* S0    = (float*)carve((size_t)DB * DB * 4);
  float* S1    = (float*)carve((size_t)DB * DB * 4);
  unsigned short* Wn_t = (unsigned short*)carve((size_t)DB * NB * 2);
  unsigned short* Wt_t = (unsigned short*)carve((size_t)NB * DB * 2);
  unsigned short* Yh   = (unsigned short*)carve((size_t)NR * DB * 2);
  unsigned short* Rh   = (unsigned short*)carve((size_t)NR * DB * 2);
  unsigned short* Zh   = (unsigned short*)carve((size_t)NR * NB * 2);
  unsigned short* Gh   = (unsigned short*)carve((size_t)NR * NB * 2);

  k_zero<<<1, 64, 0, stream>>>(slots);
  k_colnorm<<<NB / 256, 256, 0, stream>>>(W, invn);
  k_wnorm<<<dim3(NB / 32, DB / 32), 256, 0, stream>>>(W, invn, Wn_t, Wt_t);
  k_ynorm<<<1024, 256, 0, stream>>>(Y, Yh, slots);

  // power method replacement: B = Wn Wn^T, then 9 trace-normalized squarings + Rayleigh
  k_gemm_bbuild<<<dim3(DB / 64, DB / 128), 256, 0, stream>>>(Wn_t, Bmat, slots);
  float* ss[2] = {S0, S1};
  for (int k = 0; k < NSQ; ++k) {
    const float* in = (k == 0) ? Bmat : ss[(k + 1) & 1];
    k_sq<<<dim3(16, 16), 256, 0, stream>>>(in, ss[k & 1], slots + SL_TR + k, slots + SL_TR + k + 1);
  }
  k_rayleigh<<<256, 256, 0, stream>>>(Bmat, ss[(NSQ + 1) & 1], slots);
  k_derive<<<1, 64, 0, stream>>>(slots, Kp);

  // FISTA
  k_gemm_init<<<dim3(NB / 128, NR / 128), 256, 0, stream>>>(Yh, Wt_t, slots, Kp, Gh, Zh);
  double t = 1.0;
  for (int i = 0; i < ITERS; ++i) {
    k_gemm_res<<<dim3(DB / 64, NR / 128), 256, 0, stream>>>(Zh, Wn_t, Yh, Rh, slots + SL_RES2 + i);
    double tn = (1.0 + sqrt(1.0 + 4.0 * t * t)) / 2.0;
    float mom = (float)((t - 1.0) / tn);
    t = tn;
    k_gemm_upd<<<dim3(NB / 128, NR / 128), 256, 0, stream>>>(Rh, Wt_t, slots, Gh, Zh, GammaOut,
                                                             mom, (i == ITERS - 1) ? 1 : 0);
  }
  k_gemm_x<<<dim3(DB / 64, NR / 128), 256, 0, stream>>>(Gh, Wn_t, Xout);
  k_norms<<<1, 64, 0, stream>>>(slots, NormsOut);
}

// Round 4
// 2484.184 us; speedup vs baseline: 1.2871x; 1.1422x over previous
//
#include <hip/hip_runtime.h>
#include <cmath>

#define NR   8192   // rows of Y
#define DB   512    // signal dim n
#define NB   2048   // dictionary atoms m
#define ITERS 20
#define NSQ   9     // trace-normalized squarings of B

typedef _Float16 hfrag_t __attribute__((ext_vector_type(8)));  // 8 fp16 = 16B
typedef __attribute__((ext_vector_type(4))) float accv_t;      // 4 fp32
typedef unsigned short us4 __attribute__((ext_vector_type(4))); // 8B
typedef float f4 __attribute__((ext_vector_type(4)));           // 16B

// scalar slots in ws
#define SL_Y2   0
#define SL_NUM  1
#define SL_DEN  2
#define SL_C    3
#define SL_ETA  4
#define SL_THR  5
#define SL_TR   6    // 6..15  traces
#define SL_RES2 16   // 16..35 per-iter ||R||^2

__device__ inline unsigned short f2h(float f) {
  _Float16 h = (_Float16)f;
  return __builtin_bit_cast(unsigned short, h);
}
__device__ inline float h2f(unsigned short u) {
  _Float16 h = __builtin_bit_cast(_Float16, u);
  return (float)h;
}
__device__ inline float softthr(float x, float t) {
  float a = fabsf(x) - t;
  return a > 0.f ? copysignf(a, x) : 0.f;
}

// ---- Fragment-native tiled layout ----
// 16x16 tile = 256 contiguous fp16, element (m,k) at m*16+k (row-major in tile).
// A-fragment for mfma_16x16x32 (operand-swapped): lane (l16,quad) needs
// A[m=l16][k=quad*8+j] j=0..7 -> tile kt*2+(quad>>1), bytes l16*32+(quad&1)*16:
// ONE 16B load per fragment; wave covers 512B contiguous. Same for B (n,k).
// C tile: lane owns (m=l16, n=quad*4+r) -> us4 at byte l16*32+quad*8.

// ---- barrier-free MFMA GEMM core: both operands tiled, no LDS ----
// (round-0 proven form; compiler schedules loads across the unroll-4 window)
template<int MI, int NI, int NKT>
__device__ inline void gemm_tt(const unsigned short* __restrict__ At, int NTka,
                               const unsigned short* __restrict__ Bt, int NTkb,
                               int mt0, int nt0, accv_t acc[MI][NI]) {
  const int lane = threadIdx.x & 63;
  const int l16 = lane & 15, quad = lane >> 4;
  const int off = l16 * 16 + (quad & 1) * 8;   // element offset within tile
  const int kh = quad >> 1;
#pragma unroll
  for (int mi = 0; mi < MI; ++mi)
#pragma unroll
    for (int ni = 0; ni < NI; ++ni) acc[mi][ni] = (accv_t){0.f, 0.f, 0.f, 0.f};

#pragma unroll 4
  for (int kt = 0; kt < NKT; ++kt) {
    const int ktile = (kt << 1) + kh;
    hfrag_t af[MI], bf[NI];
#pragma unroll
    for (int mi = 0; mi < MI; ++mi)
      af[mi] = *(const hfrag_t*)&At[(((size_t)(mt0 + mi) * NTka + ktile) << 8) + off];
#pragma unroll
    for (int ni = 0; ni < NI; ++ni)
      bf[ni] = *(const hfrag_t*)&Bt[(((size_t)(nt0 + ni) * NTkb + ktile) << 8) + off];
#pragma unroll
    for (int mi = 0; mi < MI; ++mi)
#pragma unroll
      for (int ni = 0; ni < NI; ++ni)
        acc[mi][ni] = __builtin_amdgcn_mfma_f32_16x16x32_f16(bf[ni], af[mi], acc[mi][ni], 0, 0, 0);
  }
}

// C-tile epilogue offset (element units) for tiled fp16 surfaces
__device__ inline size_t ctile_off(int mt, int nt, int NTn) {
  int lane = threadIdx.x & 63;
  return (((size_t)mt * NTn + nt) << 8) + (lane & 15) * 16 + (lane >> 4) * 4;
}

// ---------------- small kernels ----------------
__global__ void k_zero(float* slots) { if (threadIdx.x < 64) slots[threadIdx.x] = 0.f; }

__global__ void k_colnorm(const float* __restrict__ W, float* __restrict__ invn) {
  int j = blockIdx.x * 256 + threadIdx.x;     // 2048 cols
  float s = 0.f;
  for (int i = 0; i < DB; ++i) { float v = W[(size_t)i * NB + j]; s += v * v; }
  invn[j] = 1.0f / sqrtf(s);
}

// normalize cols; emit tiled Wn_t [DB/16][NB/16] (elem (i,j)->i*16+j)
// and tiled Wt_t [NB/16][DB/16] (elem (j,i)->j*16+i)
__global__ void k_wnorm(const float* __restrict__ W, const float* __restrict__ invn,
                        unsigned short* __restrict__ Wn_t, unsigned short* __restrict__ Wt_t) {
  int tx = threadIdx.x & 31, ty = threadIdx.x >> 5;
  int j = blockIdx.x * 32 + tx;               // NB index
  float inv = invn[j];
#pragma unroll
  for (int r = 0; r < 4; ++r) {
    int i = blockIdx.y * 32 + ty + r * 8;     // DB index
    unsigned short h = f2h(W[(size_t)i * NB + j] * inv);
    Wn_t[(((size_t)(i >> 4) * (NB / 16) + (j >> 4)) << 8) + (i & 15) * 16 + (j & 15)] = h;
    Wt_t[(((size_t)(j >> 4) * (DB / 16) + (i >> 4)) << 8) + (j & 15) * 16 + (i & 15)] = h;
  }
}

// Y (row-major fp32) -> Yh (tiled fp16, 32 k-tiles per row) + ||Y||^2
__global__ void k_ynorm(const float* __restrict__ Y, unsigned short* __restrict__ Yh,
                        float* __restrict__ slots) {
  float s = 0.f;
  for (size_t u = (size_t)blockIdx.x * 256 + threadIdx.x; u < (size_t)(NR * DB / 4);
       u += (size_t)gridDim.x * 256) {
    int tile = (int)(u >> 6), r = (int)(u & 63);
    int mt = tile >> 5, nt = tile & 31;
    int m = mt * 16 + (r >> 2), n = nt * 16 + (r & 3) * 4;
    f4 v = *(const f4*)&Y[(size_t)m * DB + n];
    us4 h;
#pragma unroll
    for (int q = 0; q < 4; ++q) { h[q] = f2h(v[q]); s += v[q] * v[q]; }
    *(us4*)&Yh[u << 2] = h;
  }
  for (int off = 32; off > 0; off >>= 1) s += __shfl_xor(s, off);
  if ((threadIdx.x & 63) == 0) atomicAdd(&slots[SL_Y2], s);
}

// fp32 squaring: D = (S/tr)^2, accumulate trace(D)
__global__ __launch_bounds__(256) void k_sq(const float* __restrict__ S, float* __restrict__ D,
                                            const float* __restrict__ trIn, float* __restrict__ trOut) {
  __shared__ float tA[32][33], tB[32][33];
  int tx = threadIdx.x & 31, ty = threadIdx.x >> 5;
  int r0 = blockIdx.y * 32, c0 = blockIdx.x * 32;
  float inv = 1.0f / trIn[0];
  float acc[4] = {0.f, 0.f, 0.f, 0.f};
  for (int kt = 0; kt < 16; ++kt) {
    __syncthreads();
#pragma unroll
    for (int r = 0; r < 4; ++r) {
      tA[ty + r * 8][tx] = S[(size_t)(r0 + ty + r * 8) * DB + kt * 32 + tx];
      tB[ty + r * 8][tx] = S[(size_t)(kt * 32 + ty + r * 8) * DB + c0 + tx];
    }
    __syncthreads();
#pragma unroll
    for (int kk = 0; kk < 32; ++kk) {
      float b = tB[kk][tx];
#pragma unroll
      for (int r = 0; r < 4; ++r) acc[r] += tA[ty + r * 8][kk] * b;
    }
  }
  float inv2 = inv * inv;
#pragma unroll
  for (int r = 0; r < 4; ++r) {
    int row = r0 + ty + r * 8, col = c0 + tx;
    float v = acc[r] * inv2;
    D[(size_t)row * DB + col] = v;
    if (row == col) atomicAdd(trOut, v);
  }
}

__global__ void k_rayleigh(const float* __restrict__ Bm, const float* __restrict__ S,
                           float* __restrict__ slots) {
  int tid = blockIdx.x * 256 + threadIdx.x;
  float num = 0.f, den = 0.f;
  for (int i = tid; i < DB * DB; i += 256 * 256) {
    float s = S[i];
    num += Bm[i] * s;
    if ((i >> 9) == (i & 511)) den += s;
  }
  for (int off = 32; off > 0; off >>= 1) { num += __shfl_xor(num, off); den += __shfl_xor(den, off); }
  if ((threadIdx.x & 63) == 0) { atomicAdd(&slots[SL_NUM], num); atomicAdd(&slots[SL_DEN], den); }
}

__global__ void k_derive(float* slots, const float* __restrict__ Kp) {
  if (threadIdx.x == 0) {
    float cc = slots[SL_NUM] / slots[SL_DEN];
    slots[SL_C] = cc;
    float eta = 1.0f / cc;
    slots[SL_ETA] = eta;
    slots[SL_THR] = Kp[0] * eta;
  }
}

__global__ void k_norms(const float* __restrict__ slots, float* __restrict__ out) {
  int i = threadIdx.x;
  if (i < ITERS) out[i] = sqrtf(slots[SL_RES2 + i] / slots[SL_Y2]);
}

// ---------------- GEMM kernels (all barrier-free) ----------------
// B = Wn * Wn^T [512x512] row-major out, trace -> slots[SL_TR].
// block 128m x 64n: wave w covers mt0=8*by+w*2 (MI=2), nt0=4*bx (NI=4)
__global__ __launch_bounds__(256) void k_gemm_bbuild(const unsigned short* __restrict__ Wn_t,
                                                     float* __restrict__ Bm, float* __restrict__ slots) {
  accv_t acc[2][4];
  int w = threadIdx.x >> 6, lane = threadIdx.x & 63;
  int mt0 = blockIdx.y * 8 + w * 2, nt0 = blockIdx.x * 4;
  gemm_tt<2, 4, NB / 32>(Wn_t, NB / 16, Wn_t, NB / 16, mt0, nt0, acc);
  int l16 = lane & 15, quad = lane >> 4;
  float tr = 0.f;
#pragma unroll
  for (int mi = 0; mi < 2; ++mi)
#pragma unroll
    for (int ni = 0; ni < 4; ++ni) {
      int m = (mt0 + mi) * 16 + l16, nb = (nt0 + ni) * 16 + quad * 4;
      *(f4*)&Bm[(size_t)m * DB + nb] = acc[mi][ni];
#pragma unroll
      for (int r = 0; r < 4; ++r)
        if (m == nb + r) tr += acc[mi][ni][r];
    }
  if (tr != 0.f) atomicAdd(&slots[SL_TR], tr);
}

// Gamma0 = soft(eta*(Y@Wn), lam); Gh = Zh = Gamma0 (tiled).
// Round-0 tiles (block 128x128, wave 64x64, MI=4,NI=4) with XCD-clustered 1-D
// grid of 1024: the 16 n-groups sharing a 128-row Yh band land on one XCD.
__global__ __launch_bounds__(256) void k_gemm_init(const unsigned short* __restrict__ Yh,
                                                   const unsigned short* __restrict__ Wt_t,
                                                   const float* __restrict__ slots,
                                                   const float* __restrict__ Kp,
                                                   unsigned short* __restrict__ Gh,
                                                   unsigned short* __restrict__ Zh) {
  accv_t acc[4][4];
  int w = threadIdx.x >> 6;
  int h = blockIdx.x;
  int xcd = h & 7, slot = h >> 3;            // 128 slots per XCD
  int band = xcd * 8 + (slot >> 4);          // 64 bands of 128 rows
  int nt = slot & 15;                        // 16 n-groups of 128 cols
  int mt0 = band * 8 + (w >> 1) * 4, nt0 = nt * 8 + (w & 1) * 4;
  gemm_tt<4, 4, DB / 32>(Yh, DB / 16, Wt_t, DB / 16, mt0, nt0, acc);
  float eta = slots[SL_ETA], lam = Kp[0];
#pragma unroll
  for (int mi = 0; mi < 4; ++mi)
#pragma unroll
    for (int ni = 0; ni < 4; ++ni) {
      size_t tb = ctile_off(mt0 + mi, nt0 + ni, NB / 16);
      us4 gq;
#pragma unroll
      for (int r = 0; r < 4; ++r) gq[r] = f2h(softthr(acc[mi][ni][r] * eta, lam));
      *(us4*)&Gh[tb] = gq;
      *(us4*)&Zh[tb] = gq;
    }
}

// R = Z @ Wn^T - Y (tiled); ||R||^2.
// Round-0 tiles (block 128m x 64n, wave 32x64, MI=2,NI=4) with XCD-clustered
// 1-D grid of 512: the 8 n-blocks sharing a 128-row Zh band land on one XCD,
// so the band (512KB) + Wn (2MB) stay L2-resident.
__global__ __launch_bounds__(256) void k_gemm_res(const unsigned short* __restrict__ Zh,
                                                  const unsigned short* __restrict__ Wn_t,
                                                  const unsigned short* __restrict__ Yh,
                                                  unsigned short* __restrict__ Rh,
                                                  float* __restrict__ res2slot) {
  accv_t acc[2][4];
  int w = threadIdx.x >> 6;
  int h = blockIdx.x;
  int xcd = h & 7, slot = h >> 3;            // 64 slots per XCD
  int band = xcd * 8 + (slot >> 3);          // 64 bands of 128 rows
  int nt = slot & 7;                         // 8 n-groups of 64 cols
  int mt0 = band * 8 + w * 2, nt0 = nt * 4;
  gemm_tt<2, 4, NB / 32>(Zh, NB / 16, Wn_t, NB / 16, mt0, nt0, acc);
  float s2 = 0.f;
#pragma unroll
  for (int mi = 0; mi < 2; ++mi)
#pragma unroll
    for (int ni = 0; ni < 4; ++ni) {
      size_t tb = ctile_off(mt0 + mi, nt0 + ni, DB / 16);
      us4 yq = *(const us4*)&Yh[tb];
      us4 rq;
#pragma unroll
      for (int r = 0; r < 4; ++r) {
        float rv = acc[mi][ni][r] - h2f(yq[r]);
        rq[r] = f2h(rv);
        s2 += rv * rv;
      }
      *(us4*)&Rh[tb] = rq;
    }
  for (int off = 32; off > 0; off >>= 1) s2 += __shfl_xor(s2, off);
  if ((threadIdx.x & 63) == 0) atomicAdd(res2slot, s2);
}

// G = R @ Wn ; gn = soft(Z - eta*G, lam/c); Z = gn + mom*(gn-Gamma_old); Gh = gn.
// Round-0 tiles (block 128x128, wave 64x64, MI=4,NI=4) with XCD-clustered 1-D
// grid of 1024. last iter: exact fp32 gn -> GammaOut (row-major).
__global__ __launch_bounds__(256) void k_gemm_upd(const unsigned short* __restrict__ Rh,
                                                  const unsigned short* __restrict__ Wt_t,
                                                  const float* __restrict__ slots,
                                                  unsigned short* __restrict__ Gh,
                                                  unsigned short* __restrict__ Zh,
                                                  float* __restrict__ GammaOut,
                                                  float mom, int writeFinal) {
  accv_t acc[4][4];
  int w = threadIdx.x >> 6, lane = threadIdx.x & 63;
  int h = blockIdx.x;
  int xcd = h & 7, slot = h >> 3;            // 128 slots per XCD
  int band = xcd * 8 + (slot >> 4);          // 64 bands of 128 rows
  int nt = slot & 15;                        // 16 n-groups of 128 cols
  int mt0 = band * 8 + (w >> 1) * 4, nt0 = nt * 8 + (w & 1) * 4;
  gemm_tt<4, 4, DB / 32>(Rh, DB / 16, Wt_t, DB / 16, mt0, nt0, acc);
  int l16 = lane & 15, quad = lane >> 4;
  float eta = slots[SL_ETA], thr = slots[SL_THR];
#pragma unroll
  for (int mi = 0; mi < 4; ++mi)
#pragma unroll
    for (int ni = 0; ni < 4; ++ni) {
      size_t tb = ctile_off(mt0 + mi, nt0 + ni, NB / 16);
      us4 zq = *(const us4*)&Zh[tb];
      us4 gq = *(const us4*)&Gh[tb];
      us4 gho, zho;
      f4 gf;
#pragma unroll
      for (int r = 0; r < 4; ++r) {
        float z = h2f(zq[r]);
        float gold = h2f(gq[r]);
        float gn = softthr(z - eta * acc[mi][ni][r], thr);
        float zn = gn + mom * (gn - gold);
        gho[r] = f2h(gn);
        zho[r] = f2h(zn);
        gf[r] = gn;
      }
      *(us4*)&Gh[tb] = gho;
      *(us4*)&Zh[tb] = zho;
      if (writeFinal) {
        int m = (mt0 + mi) * 16 + l16, nb = (nt0 + ni) * 16 + quad * 4;
        *(f4*)&GammaOut[(size_t)m * NB + nb] = gf;
      }
    }
}

// X = Gamma @ Wn^T (row-major fp32 out).
// Round-0 tiles (block 128m x 64n, wave 32x64) with XCD-clustered 1-D grid 512.
__global__ __launch_bounds__(256) void k_gemm_x(const unsigned short* __restrict__ Gh,
                                                const unsigned short* __restrict__ Wn_t,
                                                float* __restrict__ X) {
  accv_t acc[2][4];
  int w = threadIdx.x >> 6, lane = threadIdx.x & 63;
  int h = blockIdx.x;
  int xcd = h & 7, slot = h >> 3;
  int band = xcd * 8 + (slot >> 3);
  int nt = slot & 7;
  int mt0 = band * 8 + w * 2, nt0 = nt * 4;
  gemm_tt<2, 4, NB / 32>(Gh, NB / 16, Wn_t, NB / 16, mt0, nt0, acc);
  int l16 = lane & 15, quad = lane >> 4;
#pragma unroll
  for (int mi = 0; mi < 2; ++mi)
#pragma unroll
    for (int ni = 0; ni < 4; ++ni) {
      int m = (mt0 + mi) * 16 + l16, nb = (nt0 + ni) * 16 + quad * 4;
      *(f4*)&X[(size_t)m * DB + nb] = acc[mi][ni];
    }
}

extern "C" void kernel_launch(void* const* d_in, const int* in_sizes, int n_in,
                              void* d_out, int out_size, void* d_ws, size_t ws_size,
                              hipStream_t stream) {
  const float* Y  = (const float*)d_in[0];
  const float* W  = (const float*)d_in[1];
  const float* Kp = (const float*)d_in[2];

  float* Xout     = (float*)d_out;
  float* GammaOut = Xout + (size_t)NR * DB;
  float* NormsOut = GammaOut + (size_t)NR * NB;

  char* p = (char*)d_ws;
  auto carve = [&](size_t bytes) -> void* {
    void* r = (void*)p; p += (bytes + 255) & ~(size_t)255; return r;
  };
  float* slots = (float*)carve(64 * 4);
  float* invn  = (float*)carve(NB * 4);
  float* Bmat  = (float*)carve((size_t)DB * DB * 4);
  float* S0    = (float*)carve((size_t)DB * DB * 4);
  float* S1    = (float*)carve((size_t)DB * DB * 4);
  unsigned short* Wn_t = (unsigned short*)carve((size_t)DB * NB * 2);
  unsigned short* Wt_t = (unsigned short*)carve((size_t)NB * DB * 2);
  unsigned short* Yh   = (unsigned short*)carve((size_t)NR * DB * 2);
  unsigned short* Rh   = (unsigned short*)carve((size_t)NR * DB * 2);
  unsigned short* Zh   = (unsigned short*)carve((size_t)NR * NB * 2);
  unsigned short* Gh   = (unsigned short*)carve((size_t)NR * NB * 2);

  k_zero<<<1, 64, 0, stream>>>(slots);
  k_colnorm<<<NB / 256, 256, 0, stream>>>(W, invn);
  k_wnorm<<<dim3(NB / 32, DB / 32), 256, 0, stream>>>(W, invn, Wn_t, Wt_t);
  k_ynorm<<<1024, 256, 0, stream>>>(Y, Yh, slots);

  // power method replacement: B = Wn Wn^T, then 9 trace-normalized squarings + Rayleigh
  k_gemm_bbuild<<<dim3(DB / 64, DB / 128), 256, 0, stream>>>(Wn_t, Bmat, slots);
  float* ss[2] = {S0, S1};
  for (int k = 0; k < NSQ; ++k) {
    const float* in = (k == 0) ? Bmat : ss[(k + 1) & 1];
    k_sq<<<dim3(16, 16), 256, 0, stream>>>(in, ss[k & 1], slots + SL_TR + k, slots + SL_TR + k + 1);
  }
  k_rayleigh<<<256, 256, 0, stream>>>(Bmat, ss[(NSQ + 1) & 1], slots);
  k_derive<<<1, 64, 0, stream>>>(slots, Kp);

  // FISTA
  k_gemm_init<<<1024, 256, 0, stream>>>(Yh, Wt_t, slots, Kp, Gh, Zh);
  double t = 1.0;
  for (int i = 0; i < ITERS; ++i) {
    k_gemm_res<<<512, 256, 0, stream>>>(Zh, Wn_t, Yh, Rh, slots + SL_RES2 + i);
    double tn = (1.0 + sqrt(1.0 + 4.0 * t * t)) / 2.0;
    float mom = (float)((t - 1.0) / tn);
    t = tn;
    k_gemm_upd<<<1024, 256, 0, stream>>>(Rh, Wt_t, slots, Gh, Zh, GammaOut,
                                         mom, (i == ITERS - 1) ? 1 : 0);
  }
  k_gemm_x<<<512, 256, 0, stream>>>(Gh, Wn_t, Xout);
  k_norms<<<1, 64, 0, stream>>>(slots, NormsOut);
}